// Round 13
// baseline (291.734 us; speedup 1.0000x reference)
//
#include <hip/hip_runtime.h>
#include <math.h>

#define N_NODES 50000
#define N_EDGES 800000
#define IN_DIM  9
#define HIDDEN  256
#define N_CAND  4096

#define SCAN_TPB 256
#define SCAN_NB  ((N_NODES + SCAN_TPB - 1) / SCAN_TPB)   // 196

// ---------------- CSR build ----------------

__global__ void hist_kernel(const int* __restrict__ dst, int* __restrict__ cnt) {
    int e = blockIdx.x * blockDim.x + threadIdx.x;
    if (e < N_EDGES) atomicAdd(&cnt[dst[e]], 1);
}

__global__ __launch_bounds__(SCAN_TPB) void scan1_kernel(const int* __restrict__ cnt,
                                                         int* __restrict__ row_ptr,
                                                         int* __restrict__ blockSums) {
    __shared__ int s[SCAN_TPB];
    int t = threadIdx.x;
    int i = blockIdx.x * SCAN_TPB + t;
    int v = (i < N_NODES) ? cnt[i] : 0;
    s[t] = v;
    __syncthreads();
#pragma unroll
    for (int off = 1; off < SCAN_TPB; off <<= 1) {
        int u = (t >= off) ? s[t - off] : 0;
        __syncthreads();
        s[t] += u;
        __syncthreads();
    }
    if (i < N_NODES) row_ptr[i] = s[t] - v;          // exclusive within block
    if (t == SCAN_TPB - 1) blockSums[blockIdx.x] = s[t];  // block total
}

__global__ __launch_bounds__(SCAN_TPB) void scan2_kernel(const int* __restrict__ blockSums,
                                                         int* __restrict__ blockOff,
                                                         int* __restrict__ row_ptr) {
    __shared__ int s[SCAN_TPB];
    int t = threadIdx.x;
    int v = (t < SCAN_NB) ? blockSums[t] : 0;
    s[t] = v;
    __syncthreads();
#pragma unroll
    for (int off = 1; off < SCAN_TPB; off <<= 1) {
        int u = (t >= off) ? s[t - off] : 0;
        __syncthreads();
        s[t] += u;
        __syncthreads();
    }
    if (t < SCAN_NB) blockOff[t] = s[t] - v;
    if (t == SCAN_TPB - 1) row_ptr[N_NODES] = s[t];
}

// Phase 3: finalize row_ptr, init cur = row_ptr (so fill's atomicAdd return IS
// the final slot -> removes the scattered row_ptr[d] read per edge), compute dinv.
__global__ __launch_bounds__(SCAN_TPB) void scan3_kernel(const int* __restrict__ cnt,
                                                         const int* __restrict__ blockOff,
                                                         int* __restrict__ row_ptr,
                                                         int* __restrict__ cur,
                                                         float* __restrict__ dinv) {
    int i = blockIdx.x * SCAN_TPB + threadIdx.x;
    if (i < N_NODES) {
        int rp = row_ptr[i] + blockOff[blockIdx.x];
        row_ptr[i] = rp;
        cur[i] = rp;
        dinv[i] = 1.0f / sqrtf((float)(cnt[i] + 1));
    }
}

// 4 edges per thread: int4 coalesced index reads, 4 independent atomic chains.
// cur pre-initialized to row_ptr, so pos = atomicAdd(&cur[d],1) directly.
__global__ void fill_kernel(const int* __restrict__ srcv, const int* __restrict__ dstv,
                            int* __restrict__ cur, int* __restrict__ col) {
    int base = (blockIdx.x * blockDim.x + threadIdx.x) * 4;
    if (base >= N_EDGES) return;   // N_EDGES % 4 == 0, so full int4 is safe
    int4 d4 = *(const int4*)(dstv + base);
    int4 s4 = *(const int4*)(srcv + base);
    int p0 = atomicAdd(&cur[d4.x], 1);
    int p1 = atomicAdd(&cur[d4.y], 1);
    int p2 = atomicAdd(&cur[d4.z], 1);
    int p3 = atomicAdd(&cur[d4.w], 1);
    col[p0] = s4.x;
    col[p1] = s4.y;
    col[p2] = s4.z;
    col[p3] = s4.w;
}

// ---------------- 256x256 fp32 transpose (for head weight streaming) --------

__global__ __launch_bounds__(256) void transpose256_kernel(const float* __restrict__ in,
                                                           float* __restrict__ out) {
    __shared__ float tile[32][33];
    int bx = blockIdx.x & 7, by = blockIdx.x >> 3;   // 8x8 grid of 32x32 tiles
    int tx = threadIdx.x & 31, ty = threadIdx.x >> 5; // 32x8 threads
#pragma unroll
    for (int k = 0; k < 4; ++k)
        tile[ty + 8 * k][tx] = in[(by * 32 + ty + 8 * k) * HIDDEN + bx * 32 + tx];
    __syncthreads();
#pragma unroll
    for (int k = 0; k < 4; ++k)
        out[(bx * 32 + ty + 8 * k) * HIDDEN + by * 32 + tx] = tile[tx][ty + 8 * k];
}

// ---------------- Layer-1 aggregation on RAW 9-dim features ----------------
// 16 lanes per node; 4-step shfl_xor reduce within aligned 16-lane groups.

__global__ __launch_bounds__(256) void aggx_kernel(const float* __restrict__ x,
                                                   const int* __restrict__ row_ptr,
                                                   const int* __restrict__ col,
                                                   const float* __restrict__ dinv,
                                                   float* __restrict__ ax) {
    int tid  = threadIdx.x;
    int node = blockIdx.x * 16 + (tid >> 4);
    int l    = tid & 15;
    if (node >= N_NODES) return;

    float a[IN_DIM];
#pragma unroll
    for (int d = 0; d < IN_DIM; ++d) a[d] = 0.f;

    int beg = row_ptr[node], end = row_ptr[node + 1];
    for (int j = beg + l; j < end; j += 16) {
        int s = col[j];
        float w = dinv[s];
        const float* xs = x + (size_t)s * IN_DIM;
#pragma unroll
        for (int d = 0; d < IN_DIM; ++d) a[d] += w * xs[d];
    }

#pragma unroll
    for (int m = 8; m >= 1; m >>= 1) {
#pragma unroll
        for (int d = 0; d < IN_DIM; ++d) a[d] += __shfl_xor(a[d], m);
    }

    float di = dinv[node];
    const float* xi = x + (size_t)node * IN_DIM;
    float o[IN_DIM];
#pragma unroll
    for (int d = 0; d < IN_DIM; ++d) o[d] = di * (di * xi[d] + a[d]);

    float v = o[0];
    if (l == 1) v = o[1];
    if (l == 2) v = o[2];
    if (l == 3) v = o[3];
    if (l == 4) v = o[4];
    if (l == 5) v = o[5];
    if (l == 6) v = o[6];
    if (l == 7) v = o[7];
    if (l == 8) v = o[8];
    if (l < IN_DIM) ax[(size_t)node * IN_DIM + l] = v;
}

// ---------------- h1 = relu(ax @ W1 + b1), all nodes ----------------

#define NPB 8
__global__ __launch_bounds__(256) void h1_kernel(const float* __restrict__ ax,
                                                 const float* __restrict__ W1,
                                                 const float* __restrict__ b1,
                                                 float* __restrict__ h1) {
    int n0 = blockIdx.x * NPB;
    int c = threadIdx.x;
    __shared__ float s[NPB][IN_DIM];
    if (c < NPB * IN_DIM) s[c / IN_DIM][c % IN_DIM] = ax[(size_t)n0 * IN_DIM + c];
    __syncthreads();
    float w[IN_DIM];
#pragma unroll
    for (int k = 0; k < IN_DIM; ++k) w[k] = W1[k * HIDDEN + c];
    float b = b1[c];
#pragma unroll
    for (int r = 0; r < NPB; ++r) {
        float acc = b;
#pragma unroll
        for (int k = 0; k < IN_DIM; ++k) acc += s[r][k] * w[k];
        h1[(size_t)(n0 + r) * HIDDEN + c] = fmaxf(acc, 0.f);
    }
}

// ---------------- Candidate-only aggregation of h1 ----------------

__global__ __launch_bounds__(256) void aggc_kernel(const float* __restrict__ h1,
                                                   const int* __restrict__ cand,
                                                   const int* __restrict__ row_ptr,
                                                   const int* __restrict__ col,
                                                   const float* __restrict__ dinv,
                                                   float* __restrict__ g) {
    int k = blockIdx.x * 4 + (threadIdx.x >> 6);
    if (k >= N_CAND) return;
    int lane = threadIdx.x & 63;
    int node = cand[k];
    const float di = dinv[node];
    float4 v = ((const float4*)(h1 + (size_t)node * HIDDEN))[lane];
    float4 acc = make_float4(di * v.x, di * v.y, di * v.z, di * v.w);
    int j = row_ptr[node], end = row_ptr[node + 1];
    for (; j < end; ++j) {
        int s = col[j];
        float w = dinv[s];
        float4 mv = ((const float4*)(h1 + (size_t)s * HIDDEN))[lane];
        acc.x += w * mv.x; acc.y += w * mv.y; acc.z += w * mv.z; acc.w += w * mv.w;
    }
    float4 o = make_float4(di * acc.x, di * acc.y, di * acc.z, di * acc.w);
    ((float4*)(g + (size_t)k * HIDDEN))[lane] = o;
}

// ---------------- Fused candidate head ----------------
// CPB=4, no unroll pragma, no min-waves bound (R9: those spilled).
// NEW: weights pre-transposed (w2t[c][i] = W2[i][c]) so thread c streams its
// column as contiguous float4 -> 1 b128 load per 16 FMAs (was 4 dword loads),
// per-thread sequential L1 streaming. FLOP order identical to R8 form.

#define CPB 4
__global__ __launch_bounds__(256) void head_fused_kernel(const float* __restrict__ g,
                                                         const float* __restrict__ w2t,
                                                         const float* __restrict__ b2,
                                                         const float* __restrict__ wh1t,
                                                         const float* __restrict__ bh1,
                                                         const float* __restrict__ Wh2,
                                                         const float* __restrict__ bh2,
                                                         float* __restrict__ out) {
    __shared__ float A[CPB][HIDDEN];
    __shared__ float B[CPB][HIDDEN];
    __shared__ float red[CPB][4];
    int k0 = blockIdx.x * CPB;
    int c = threadIdx.x;

#pragma unroll
    for (int r = 0; r < CPB; ++r) A[r][c] = g[(size_t)(k0 + r) * HIDDEN + c];
    __syncthreads();

    // stage 1: h2 = relu(A @ W2 + b2)
    float acc[CPB];
    {
        float b = b2[c];
#pragma unroll
        for (int r = 0; r < CPB; ++r) acc[r] = b;
        const float* wrow = w2t + (size_t)c * HIDDEN;
        for (int i = 0; i < HIDDEN; i += 4) {
            float4 w = *(const float4*)(wrow + i);
#pragma unroll
            for (int r = 0; r < CPB; ++r) {
                float4 a = *(const float4*)&A[r][i];
                acc[r] += a.x * w.x + a.y * w.y + a.z * w.z + a.w * w.w;
            }
        }
#pragma unroll
        for (int r = 0; r < CPB; ++r) B[r][c] = fmaxf(acc[r], 0.f);
    }
    __syncthreads();

    // stage 2: t = tanh(B @ Wh1 + bh1); p = t * Wh2[c]
    {
        float b = bh1[c];
#pragma unroll
        for (int r = 0; r < CPB; ++r) acc[r] = b;
        const float* wrow = wh1t + (size_t)c * HIDDEN;
        for (int i = 0; i < HIDDEN; i += 4) {
            float4 w = *(const float4*)(wrow + i);
#pragma unroll
            for (int r = 0; r < CPB; ++r) {
                float4 a = *(const float4*)&B[r][i];
                acc[r] += a.x * w.x + a.y * w.y + a.z * w.z + a.w * w.w;
            }
        }
        float w2c = Wh2[c];
#pragma unroll
        for (int r = 0; r < CPB; ++r) acc[r] = tanhf(acc[r]) * w2c;
    }

    // per-row reduction over 256 threads (4 waves)
#pragma unroll
    for (int r = 0; r < CPB; ++r) {
        float v = acc[r];
#pragma unroll
        for (int off = 32; off > 0; off >>= 1) v += __shfl_down(v, off);
        if ((c & 63) == 0) red[r][c >> 6] = v;
    }
    __syncthreads();
    if (c < CPB) out[k0 + c] = red[c][0] + red[c][1] + red[c][2] + red[c][3] + bh2[0];
}

// ---------------- launch ----------------

extern "C" void kernel_launch(void* const* d_in, const int* in_sizes, int n_in,
                              void* d_out, int out_size, void* d_ws, size_t ws_size,
                              hipStream_t stream) {
    const float* x   = (const float*)d_in[0];
    const float* W1  = (const float*)d_in[1];
    const float* b1  = (const float*)d_in[2];
    const float* W2  = (const float*)d_in[3];
    const float* b2  = (const float*)d_in[4];
    const float* Wh1 = (const float*)d_in[5];
    const float* bh1 = (const float*)d_in[6];
    const float* Wh2 = (const float*)d_in[7];
    const float* bh2 = (const float*)d_in[8];
    const int* edge_index = (const int*)d_in[9];   // [2, E]: src then dst
    const int* cand       = (const int*)d_in[10];
    float* out = (float*)d_out;

    char* ws = (char*)d_ws;
    size_t off = 0;
    auto alloc = [&](size_t bytes) -> void* {
        void* p = ws + off;
        off += (bytes + 255) & ~(size_t)255;
        return p;
    };
    int*   cnt       = (int*)alloc((size_t)N_NODES * 4);
    int*   row_ptr   = (int*)alloc((size_t)(N_NODES + 1) * 4);
    int*   cur       = (int*)alloc((size_t)N_NODES * 4);
    float* dinv      = (float*)alloc((size_t)N_NODES * 4);
    int*   blockSums = (int*)alloc((size_t)SCAN_NB * 4);
    int*   blockOff  = (int*)alloc((size_t)SCAN_NB * 4);
    int*   col       = (int*)alloc((size_t)N_EDGES * 4);
    float* ax        = (float*)alloc((size_t)N_NODES * IN_DIM * 4);
    float* h1        = (float*)alloc((size_t)N_NODES * HIDDEN * 4);
    float* g         = (float*)alloc((size_t)N_CAND * HIDDEN * 4);
    float* w2t       = (float*)alloc((size_t)HIDDEN * HIDDEN * 4);
    float* wh1t      = (float*)alloc((size_t)HIDDEN * HIDDEN * 4);

    const int* src = edge_index;
    const int* dst = edge_index + N_EDGES;

    hipMemsetAsync(cnt, 0, (size_t)N_NODES * 4, stream);

    const int EB = (N_EDGES + 255) / 256;
    hist_kernel<<<EB, 256, 0, stream>>>(dst, cnt);
    scan1_kernel<<<SCAN_NB, SCAN_TPB, 0, stream>>>(cnt, row_ptr, blockSums);
    scan2_kernel<<<1, SCAN_TPB, 0, stream>>>(blockSums, blockOff, row_ptr);
    scan3_kernel<<<SCAN_NB, SCAN_TPB, 0, stream>>>(cnt, blockOff, row_ptr, cur, dinv);
    fill_kernel<<<(N_EDGES / 4 + 255) / 256, 256, 0, stream>>>(src, dst, cur, col);

    transpose256_kernel<<<64, 256, 0, stream>>>(W2, w2t);
    transpose256_kernel<<<64, 256, 0, stream>>>(Wh1, wh1t);

    aggx_kernel<<<(N_NODES + 15) / 16, 256, 0, stream>>>(x, row_ptr, col, dinv, ax);
    h1_kernel<<<N_NODES / NPB, 256, 0, stream>>>(ax, W1, b1, h1);
    aggc_kernel<<<(N_CAND + 3) / 4, 256, 0, stream>>>(h1, cand, row_ptr, col, dinv, g);
    head_fused_kernel<<<N_CAND / CPB, 256, 0, stream>>>(g, w2t, b2, wh1t, bh1, Wh2, bh2, out);
}

// Round 15
// 264.171 us; speedup vs baseline: 1.1043x; 1.1043x over previous
//
#include <hip/hip_runtime.h>
#include <math.h>

#define N_NODES 50000
#define N_EDGES 800000
#define IN_DIM  9
#define HIDDEN  256
#define N_CAND  4096

#define SCAN_TPB 256
#define SCAN_NB  ((N_NODES + SCAN_TPB - 1) / SCAN_TPB)   // 196

// ---------------- CSR build ----------------

// 4 edges per thread, int4 coalesced index reads.
__global__ void hist_kernel(const int* __restrict__ dst, int* __restrict__ cnt) {
    int base = (blockIdx.x * blockDim.x + threadIdx.x) * 4;
    if (base >= N_EDGES) return;   // N_EDGES % 4 == 0
    int4 d4 = *(const int4*)(dst + base);
    atomicAdd(&cnt[d4.x], 1);
    atomicAdd(&cnt[d4.y], 1);
    atomicAdd(&cnt[d4.z], 1);
    atomicAdd(&cnt[d4.w], 1);
}

__global__ __launch_bounds__(SCAN_TPB) void scan1_kernel(const int* __restrict__ cnt,
                                                         int* __restrict__ row_ptr,
                                                         int* __restrict__ blockSums) {
    __shared__ int s[SCAN_TPB];
    int t = threadIdx.x;
    int i = blockIdx.x * SCAN_TPB + t;
    int v = (i < N_NODES) ? cnt[i] : 0;
    s[t] = v;
    __syncthreads();
#pragma unroll
    for (int off = 1; off < SCAN_TPB; off <<= 1) {
        int u = (t >= off) ? s[t - off] : 0;
        __syncthreads();
        s[t] += u;
        __syncthreads();
    }
    if (i < N_NODES) row_ptr[i] = s[t] - v;          // exclusive within block
    if (t == SCAN_TPB - 1) blockSums[blockIdx.x] = s[t];  // block total
}

__global__ __launch_bounds__(SCAN_TPB) void scan2_kernel(const int* __restrict__ blockSums,
                                                         int* __restrict__ blockOff,
                                                         int* __restrict__ row_ptr) {
    __shared__ int s[SCAN_TPB];
    int t = threadIdx.x;
    int v = (t < SCAN_NB) ? blockSums[t] : 0;
    s[t] = v;
    __syncthreads();
#pragma unroll
    for (int off = 1; off < SCAN_TPB; off <<= 1) {
        int u = (t >= off) ? s[t - off] : 0;
        __syncthreads();
        s[t] += u;
        __syncthreads();
    }
    if (t < SCAN_NB) blockOff[t] = s[t] - v;
    if (t == SCAN_TPB - 1) row_ptr[N_NODES] = s[t];
}

// Phase 3: finalize row_ptr, init cur = row_ptr (fill's atomicAdd return IS the
// final slot -> no scattered row_ptr[d] read per edge), compute dinv.
__global__ __launch_bounds__(SCAN_TPB) void scan3_kernel(const int* __restrict__ cnt,
                                                         const int* __restrict__ blockOff,
                                                         int* __restrict__ row_ptr,
                                                         int* __restrict__ cur,
                                                         float* __restrict__ dinv) {
    int i = blockIdx.x * SCAN_TPB + threadIdx.x;
    if (i < N_NODES) {
        int rp = row_ptr[i] + blockOff[blockIdx.x];
        row_ptr[i] = rp;
        cur[i] = rp;
        dinv[i] = 1.0f / sqrtf((float)(cnt[i] + 1));
    }
}

// 4 edges per thread: int4 coalesced index reads, 4 independent atomic chains.
__global__ void fill_kernel(const int* __restrict__ srcv, const int* __restrict__ dstv,
                            int* __restrict__ cur, int* __restrict__ col) {
    int base = (blockIdx.x * blockDim.x + threadIdx.x) * 4;
    if (base >= N_EDGES) return;   // N_EDGES % 4 == 0
    int4 d4 = *(const int4*)(dstv + base);
    int4 s4 = *(const int4*)(srcv + base);
    int p0 = atomicAdd(&cur[d4.x], 1);
    int p1 = atomicAdd(&cur[d4.y], 1);
    int p2 = atomicAdd(&cur[d4.z], 1);
    int p3 = atomicAdd(&cur[d4.w], 1);
    col[p0] = s4.x;
    col[p1] = s4.y;
    col[p2] = s4.z;
    col[p3] = s4.w;
}

// ---------------- Layer-1 aggregation on RAW 9-dim features ----------------
// 16 lanes per node; 4-step shfl_xor reduce within aligned 16-lane groups.

__global__ __launch_bounds__(256) void aggx_kernel(const float* __restrict__ x,
                                                   const int* __restrict__ row_ptr,
                                                   const int* __restrict__ col,
                                                   const float* __restrict__ dinv,
                                                   float* __restrict__ ax) {
    int tid  = threadIdx.x;
    int node = blockIdx.x * 16 + (tid >> 4);
    int l    = tid & 15;
    if (node >= N_NODES) return;

    float a[IN_DIM];
#pragma unroll
    for (int d = 0; d < IN_DIM; ++d) a[d] = 0.f;

    int beg = row_ptr[node], end = row_ptr[node + 1];
    for (int j = beg + l; j < end; j += 16) {
        int s = col[j];
        float w = dinv[s];
        const float* xs = x + (size_t)s * IN_DIM;
#pragma unroll
        for (int d = 0; d < IN_DIM; ++d) a[d] += w * xs[d];
    }

#pragma unroll
    for (int m = 8; m >= 1; m >>= 1) {
#pragma unroll
        for (int d = 0; d < IN_DIM; ++d) a[d] += __shfl_xor(a[d], m);
    }

    float di = dinv[node];
    const float* xi = x + (size_t)node * IN_DIM;
    float o[IN_DIM];
#pragma unroll
    for (int d = 0; d < IN_DIM; ++d) o[d] = di * (di * xi[d] + a[d]);

    float v = o[0];
    if (l == 1) v = o[1];
    if (l == 2) v = o[2];
    if (l == 3) v = o[3];
    if (l == 4) v = o[4];
    if (l == 5) v = o[5];
    if (l == 6) v = o[6];
    if (l == 7) v = o[7];
    if (l == 8) v = o[8];
    if (l < IN_DIM) ax[(size_t)node * IN_DIM + l] = v;
}

// ---------------- h1 = relu(ax @ W1 + b1), all nodes ----------------

#define NPB 8
__global__ __launch_bounds__(256) void h1_kernel(const float* __restrict__ ax,
                                                 const float* __restrict__ W1,
                                                 const float* __restrict__ b1,
                                                 float* __restrict__ h1) {
    int n0 = blockIdx.x * NPB;
    int c = threadIdx.x;
    __shared__ float s[NPB][IN_DIM];
    if (c < NPB * IN_DIM) s[c / IN_DIM][c % IN_DIM] = ax[(size_t)n0 * IN_DIM + c];
    __syncthreads();
    float w[IN_DIM];
#pragma unroll
    for (int k = 0; k < IN_DIM; ++k) w[k] = W1[k * HIDDEN + c];
    float b = b1[c];
#pragma unroll
    for (int r = 0; r < NPB; ++r) {
        float acc = b;
#pragma unroll
        for (int k = 0; k < IN_DIM; ++k) acc += s[r][k] * w[k];
        h1[(size_t)(n0 + r) * HIDDEN + c] = fmaxf(acc, 0.f);
    }
}

// ---------------- Candidate-only aggregation of h1 ----------------

__global__ __launch_bounds__(256) void aggc_kernel(const float* __restrict__ h1,
                                                   const int* __restrict__ cand,
                                                   const int* __restrict__ row_ptr,
                                                   const int* __restrict__ col,
                                                   const float* __restrict__ dinv,
                                                   float* __restrict__ g) {
    int k = blockIdx.x * 4 + (threadIdx.x >> 6);
    if (k >= N_CAND) return;
    int lane = threadIdx.x & 63;
    int node = cand[k];
    const float di = dinv[node];
    float4 v = ((const float4*)(h1 + (size_t)node * HIDDEN))[lane];
    float4 acc = make_float4(di * v.x, di * v.y, di * v.z, di * v.w);
    int j = row_ptr[node], end = row_ptr[node + 1];
    for (; j < end; ++j) {
        int s = col[j];
        float w = dinv[s];
        float4 mv = ((const float4*)(h1 + (size_t)s * HIDDEN))[lane];
        acc.x += w * mv.x; acc.y += w * mv.y; acc.z += w * mv.z; acc.w += w * mv.w;
    }
    float4 o = make_float4(di * acc.x, di * acc.y, di * acc.z, di * acc.w);
    ((float4*)(g + (size_t)k * HIDDEN))[lane] = o;
}

// ---------------- Fused candidate head (R8 body, CPB=2) ----------------
// R8 measured: CPB=16 -> 70us, CPB=4 -> 44us (1 resp. 4 waves/SIMD). Gradient
// says more blocks = better latency hiding: CPB=2 -> 2048 blocks = 8/CU = 8
// waves/SIMD. Weight access stays the R8 LANE-COALESCED W2[i*256+c] pattern
// (R13 lesson: per-thread-contiguous "streaming" is wave-divergent, 44->70us).
// No unroll pragma / no min-waves bound (R9 lesson: spill 44->111us).

#define CPB 2
__global__ __launch_bounds__(256) void head_fused_kernel(const float* __restrict__ g,
                                                         const float* __restrict__ W2,
                                                         const float* __restrict__ b2,
                                                         const float* __restrict__ Wh1,
                                                         const float* __restrict__ bh1,
                                                         const float* __restrict__ Wh2,
                                                         const float* __restrict__ bh2,
                                                         float* __restrict__ out) {
    __shared__ float A[CPB][HIDDEN];
    __shared__ float B[CPB][HIDDEN];
    __shared__ float red[CPB][4];
    int k0 = blockIdx.x * CPB;
    int c = threadIdx.x;

#pragma unroll
    for (int r = 0; r < CPB; ++r) A[r][c] = g[(size_t)(k0 + r) * HIDDEN + c];
    __syncthreads();

    // stage 1: h2 = relu(A @ W2 + b2)
    float acc[CPB];
    {
        float b = b2[c];
#pragma unroll
        for (int r = 0; r < CPB; ++r) acc[r] = b;
        for (int i = 0; i < HIDDEN; i += 4) {
            float w0 = W2[(i + 0) * HIDDEN + c];
            float w1 = W2[(i + 1) * HIDDEN + c];
            float w2 = W2[(i + 2) * HIDDEN + c];
            float w3 = W2[(i + 3) * HIDDEN + c];
#pragma unroll
            for (int r = 0; r < CPB; ++r) {
                float4 a = *(const float4*)&A[r][i];
                acc[r] += a.x * w0 + a.y * w1 + a.z * w2 + a.w * w3;
            }
        }
#pragma unroll
        for (int r = 0; r < CPB; ++r) B[r][c] = fmaxf(acc[r], 0.f);
    }
    __syncthreads();

    // stage 2: t = tanh(B @ Wh1 + bh1); p = t * Wh2[c]
    {
        float b = bh1[c];
#pragma unroll
        for (int r = 0; r < CPB; ++r) acc[r] = b;
        for (int i = 0; i < HIDDEN; i += 4) {
            float w0 = Wh1[(i + 0) * HIDDEN + c];
            float w1 = Wh1[(i + 1) * HIDDEN + c];
            float w2 = Wh1[(i + 2) * HIDDEN + c];
            float w3 = Wh1[(i + 3) * HIDDEN + c];
#pragma unroll
            for (int r = 0; r < CPB; ++r) {
                float4 a = *(const float4*)&B[r][i];
                acc[r] += a.x * w0 + a.y * w1 + a.z * w2 + a.w * w3;
            }
        }
        float w2c = Wh2[c];
#pragma unroll
        for (int r = 0; r < CPB; ++r) acc[r] = tanhf(acc[r]) * w2c;
    }

    // per-row reduction over 256 threads (4 waves)
#pragma unroll
    for (int r = 0; r < CPB; ++r) {
        float v = acc[r];
#pragma unroll
        for (int off = 32; off > 0; off >>= 1) v += __shfl_down(v, off);
        if ((c & 63) == 0) red[r][c >> 6] = v;
    }
    __syncthreads();
    if (c < CPB) out[k0 + c] = red[c][0] + red[c][1] + red[c][2] + red[c][3] + bh2[0];
}

// ---------------- launch ----------------

extern "C" void kernel_launch(void* const* d_in, const int* in_sizes, int n_in,
                              void* d_out, int out_size, void* d_ws, size_t ws_size,
                              hipStream_t stream) {
    const float* x   = (const float*)d_in[0];
    const float* W1  = (const float*)d_in[1];
    const float* b1  = (const float*)d_in[2];
    const float* W2  = (const float*)d_in[3];
    const float* b2  = (const float*)d_in[4];
    const float* Wh1 = (const float*)d_in[5];
    const float* bh1 = (const float*)d_in[6];
    const float* Wh2 = (const float*)d_in[7];
    const float* bh2 = (const float*)d_in[8];
    const int* edge_index = (const int*)d_in[9];   // [2, E]: src then dst
    const int* cand       = (const int*)d_in[10];
    float* out = (float*)d_out;

    char* ws = (char*)d_ws;
    size_t off = 0;
    auto alloc = [&](size_t bytes) -> void* {
        void* p = ws + off;
        off += (bytes + 255) & ~(size_t)255;
        return p;
    };
    int*   cnt       = (int*)alloc((size_t)N_NODES * 4);
    int*   row_ptr   = (int*)alloc((size_t)(N_NODES + 1) * 4);
    int*   cur       = (int*)alloc((size_t)N_NODES * 4);
    float* dinv      = (float*)alloc((size_t)N_NODES * 4);
    int*   blockSums = (int*)alloc((size_t)SCAN_NB * 4);
    int*   blockOff  = (int*)alloc((size_t)SCAN_NB * 4);
    int*   col       = (int*)alloc((size_t)N_EDGES * 4);
    float* ax        = (float*)alloc((size_t)N_NODES * IN_DIM * 4);
    float* h1        = (float*)alloc((size_t)N_NODES * HIDDEN * 4);
    float* g         = (float*)alloc((size_t)N_CAND * HIDDEN * 4);

    const int* src = edge_index;
    const int* dst = edge_index + N_EDGES;

    hipMemsetAsync(cnt, 0, (size_t)N_NODES * 4, stream);

    const int E4B = (N_EDGES / 4 + 255) / 256;
    hist_kernel<<<E4B, 256, 0, stream>>>(dst, cnt);
    scan1_kernel<<<SCAN_NB, SCAN_TPB, 0, stream>>>(cnt, row_ptr, blockSums);
    scan2_kernel<<<1, SCAN_TPB, 0, stream>>>(blockSums, blockOff, row_ptr);
    scan3_kernel<<<SCAN_NB, SCAN_TPB, 0, stream>>>(cnt, blockOff, row_ptr, cur, dinv);
    fill_kernel<<<E4B, 256, 0, stream>>>(src, dst, cur, col);

    aggx_kernel<<<(N_NODES + 15) / 16, 256, 0, stream>>>(x, row_ptr, col, dinv, ax);
    h1_kernel<<<N_NODES / NPB, 256, 0, stream>>>(ax, W1, b1, h1);
    aggc_kernel<<<(N_CAND + 3) / 4, 256, 0, stream>>>(h1, cand, row_ptr, col, dinv, g);
    head_fused_kernel<<<N_CAND / CPB, 256, 0, stream>>>(g, W2, b2, Wh1, bh1, Wh2, bh2, out);
}